// Round 2
// baseline (376.909 us; speedup 1.0000x reference)
//
#include <hip/hip_runtime.h>
#include <cfloat>
#include <math.h>

#define B  32
#define T  2048
#define HD 512
#define HE 1024
#define DH 1024
#define NCMAX 16
#define G  8   // rows per group in the online-softmax loop

// ---------------------------------------------------------------------------
// Kernel 0: hwh[b] = dot(concat(hidden[0,b,:], hidden[1,b,:]), W[0:DH]) + b0
// ---------------------------------------------------------------------------
__global__ __launch_bounds__(256) void k_hwh(const float* __restrict__ hidden,
                                             const float* __restrict__ W,
                                             const float* __restrict__ bvec,
                                             float* __restrict__ hwh) {
    const int b   = blockIdx.x;
    const int tid = threadIdx.x;
    const int i0  = tid * 4;  // element index into concatenated hid (0..1023)
    // hid_cat[b][i]: i<512 -> hidden[0][b][i]; else hidden[1][b][i-512]
    const float* src = (i0 < HD) ? (hidden + (size_t)b * HD + i0)
                                 : (hidden + (size_t)B * HD + (size_t)b * HD + (i0 - HD));
    float4 h4 = *reinterpret_cast<const float4*>(src);
    float4 w4 = *reinterpret_cast<const float4*>(W + i0);
    float p = h4.x * w4.x + h4.y * w4.y + h4.z * w4.z + h4.w * w4.w;
    #pragma unroll
    for (int off = 32; off; off >>= 1) p += __shfl_xor(p, off);
    __shared__ float wsum[4];
    const int wave = tid >> 6, lane = tid & 63;
    if (lane == 0) wsum[wave] = p;
    __syncthreads();
    if (tid == 0) hwh[b] = wsum[0] + wsum[1] + wsum[2] + wsum[3] + bvec[0];
}

// ---------------------------------------------------------------------------
// Kernel 1: fused energies + online masked softmax + context accumulation.
// One block per (b, chunk). Single pass over encoder_outputs.
// ---------------------------------------------------------------------------
__global__ __launch_bounds__(256) void k_main(const float* __restrict__ enc,
                                              const float* __restrict__ mask,
                                              const float* __restrict__ W,
                                              const float* __restrict__ hwh,
                                              float* __restrict__ pctx,
                                              float* __restrict__ pm,
                                              float* __restrict__ ps,
                                              int nc) {
    const int bx  = blockIdx.x;
    const int b   = bx / nc;
    const int c   = bx % nc;
    const int tc  = T / nc;
    const int tid = threadIdx.x;
    const int wave = tid >> 6, lane = tid & 63;

    // Thread's slice of We (matches the float4 of each enc row it loads).
    const float4 We4 = *reinterpret_cast<const float4*>(W + DH + tid * 4);
    const float  hb  = hwh[b];

    const float* encb  = enc  + (size_t)b * T * HE;
    const float* maskb = mask + (size_t)b * T;
    const int t0 = c * tc;

    float  m = -FLT_MAX;
    float  s = 0.f;
    float4 ctx = {0.f, 0.f, 0.f, 0.f};

    __shared__ float wpart[4][G];

    for (int g0 = 0; g0 < tc; g0 += G) {
        float4 v[G];
        float  p[G];
        #pragma unroll
        for (int g = 0; g < G; ++g) {
            const float* row = encb + (size_t)(t0 + g0 + g) * HE + tid * 4;
            v[g] = *reinterpret_cast<const float4*>(row);
            p[g] = v[g].x * We4.x + v[g].y * We4.y + v[g].z * We4.z + v[g].w * We4.w;
        }
        // wave-level butterfly reduce for each row's dot
        #pragma unroll
        for (int g = 0; g < G; ++g) {
            #pragma unroll
            for (int off = 32; off; off >>= 1) p[g] += __shfl_xor(p[g], off);
        }
        if (lane == 0) {
            #pragma unroll
            for (int g = 0; g < G; ++g) wpart[wave][g] = p[g];
        }
        __syncthreads();

        float e[G];
        float gm = -FLT_MAX;
        #pragma unroll
        for (int g = 0; g < G; ++g) {
            float eg = wpart[0][g] + wpart[1][g] + wpart[2][g] + wpart[3][g] + hb;
            float mk = maskb[t0 + g0 + g];
            e[g] = (mk > 0.5f) ? eg : -FLT_MAX;
            gm = fmaxf(gm, e[g]);
        }
        const float mn    = fmaxf(m, gm);
        const float scale = __expf(m - mn);   // exp(0)=1 when both -FLT_MAX; ->0 when m stale
        float wsum = 0.f;
        float w[G];
        #pragma unroll
        for (int g = 0; g < G; ++g) {
            w[g] = (e[g] > -0.5f * FLT_MAX) ? __expf(e[g] - mn) : 0.f;
            wsum += w[g];
        }
        s = s * scale + wsum;
        ctx.x *= scale; ctx.y *= scale; ctx.z *= scale; ctx.w *= scale;
        #pragma unroll
        for (int g = 0; g < G; ++g) {
            ctx.x += w[g] * v[g].x;
            ctx.y += w[g] * v[g].y;
            ctx.z += w[g] * v[g].z;
            ctx.w += w[g] * v[g].w;
        }
        m = mn;
        __syncthreads();  // protect wpart before next group's writes
    }

    // write partials (unnormalized, relative to running max m)
    *reinterpret_cast<float4*>(pctx + (size_t)bx * HE + tid * 4) = ctx;
    if (tid == 0) { pm[bx] = m; ps[bx] = s; }
}

// ---------------------------------------------------------------------------
// Kernel 2: combine per-chunk partials with log-sum-exp rescale, normalize.
// ---------------------------------------------------------------------------
__global__ __launch_bounds__(256) void k_combine(const float* __restrict__ pctx,
                                                 const float* __restrict__ pm,
                                                 const float* __restrict__ ps,
                                                 float* __restrict__ out,
                                                 int nc) {
    const int b   = blockIdx.x;
    const int tid = threadIdx.x;

    float M = -FLT_MAX;
    for (int c = 0; c < nc; ++c) M = fmaxf(M, pm[b * nc + c]);
    float S = 0.f;
    for (int c = 0; c < nc; ++c) {
        float mc = pm[b * nc + c];
        float f  = (mc > -0.5f * FLT_MAX) ? __expf(mc - M) : 0.f;
        S += f * ps[b * nc + c];
    }
    float4 acc = {0.f, 0.f, 0.f, 0.f};
    for (int c = 0; c < nc; ++c) {
        float mc = pm[b * nc + c];
        float f  = (mc > -0.5f * FLT_MAX) ? __expf(mc - M) : 0.f;
        float4 v = *reinterpret_cast<const float4*>(pctx + (size_t)(b * nc + c) * HE + tid * 4);
        acc.x += f * v.x; acc.y += f * v.y; acc.z += f * v.z; acc.w += f * v.w;
    }
    const float inv = 1.f / S;
    float4 o = {acc.x * inv, acc.y * inv, acc.z * inv, acc.w * inv};
    *reinterpret_cast<float4*>(out + (size_t)b * HE + tid * 4) = o;
}

// ---------------------------------------------------------------------------
extern "C" void kernel_launch(void* const* d_in, const int* in_sizes, int n_in,
                              void* d_out, int out_size, void* d_ws, size_t ws_size,
                              hipStream_t stream) {
    const float* hidden = (const float*)d_in[0];
    const float* enc    = (const float*)d_in[1];
    const float* mask   = (const float*)d_in[2];
    const float* W      = (const float*)d_in[3];
    const float* bvec   = (const float*)d_in[4];
    float* out = (float*)d_out;

    // pick chunk count that fits the workspace (pctx is the big item)
    int nc = NCMAX;
    while (nc > 1) {
        size_t need = (size_t)B * nc * HE * sizeof(float)      // pctx
                    + 2 * (size_t)B * nc * sizeof(float)       // pm, ps
                    + 256;                                     // hwh + slack
        if (need <= ws_size) break;
        nc >>= 1;
    }

    char*  wsb  = (char*)d_ws;
    float* pctx = (float*)wsb;
    float* pm   = (float*)(wsb + (size_t)B * nc * HE * sizeof(float));
    float* ps   = pm + B * nc;
    float* hwh  = ps + B * nc;

    k_hwh   <<<B,      256, 0, stream>>>(hidden, W, bvec, hwh);
    k_main  <<<B * nc, 256, 0, stream>>>(enc, mask, W, hwh, pctx, pm, ps, nc);
    k_combine<<<B,     256, 0, stream>>>(pctx, pm, ps, out, nc);
}